// Round 19
// baseline (136.405 us; speedup 1.0000x reference)
//
#include <hip/hip_runtime.h>
#include <hip/hip_bf16.h>

#define B_SZ 4096
#define N_SZ 200
#define NU_SZ 100000

// workspace offsets (4-byte units)
#define OFF_BFRAG 0        // 12288 u32: W-fragments (layers 0..2)
#define OFF_AW1BT 12288    // 4096 f32
#define OFF_ERC   16384    // 384  f32
#define OFF_QC    16768    // B*64 f32
#define OFF_AGG   278912   // B*64 f32 (atomic)
#define OFF_SC    541056   // B f32 (atomic)
#define OFF_W32F  545152   // 4096 u32: composite W32 = AW1a @ W2 fragments (hi rows)
#define OFF_AB1C  549248   // 64 f32: ab1 + AW1a @ b2
#define OFF_H1U   549312   // NU*64 f32
#define WS_NEED_BYTES ((size_t)(OFF_H1U + NU_SZ * 64) * 4)

typedef __attribute__((ext_vector_type(8))) __bf16 bf16x8;
typedef __attribute__((ext_vector_type(4))) __bf16 bf16x4;
typedef __attribute__((ext_vector_type(4))) float f32x4;
typedef __attribute__((ext_vector_type(4))) unsigned u32x4;

__device__ __forceinline__ void split2(float x, unsigned &hi, unsigned &lo) {
    unsigned u = __float_as_uint(x);
    hi = (u + 0x7FFFu + ((u >> 16) & 1u)) >> 16;
    float r = x - __uint_as_float(hi << 16);
    unsigned ul = __float_as_uint(r);
    lo = (ul + 0x7FFFu + ((ul >> 16) & 1u)) >> 16;
}

__device__ __forceinline__ unsigned packbf(float e0, float e1) {
    __bf16 h0 = (__bf16)e0, h1 = (__bf16)e1;
    return ((unsigned)__builtin_bit_cast(unsigned short, h1) << 16) |
           (unsigned)__builtin_bit_cast(unsigned short, h0);
}

// ---------- prep1 ----------
__global__ void prep1(const float* __restrict__ gu_w1, const float* __restrict__ gu_b1,
                      const float* __restrict__ gu_w2, const float* __restrict__ att_w1,
                      const float* __restrict__ rate_emb, float* __restrict__ ws) {
    const int t0 = blockIdx.x * blockDim.x + threadIdx.x;
    const int stride = blockDim.x * gridDim.x;
    unsigned* wsu = (unsigned*)ws;
    for (int i = t0; i < 12288; i += stride) {
        int frag = i >> 8, within = i & 255, lane = within >> 2, r = within & 3;
        int hl = frag & 1, ct = (frag >> 1) & 3, kt = (frag >> 3) & 1, layer = frag >> 4;
        int col = ct * 16 + (lane & 15);
        int d0 = kt * 32 + 8 * (lane >> 4) + 2 * r;
        float w0, w1v;
        if (layer == 0)      { w0 = gu_w1[col * 128 + d0];  w1v = gu_w1[col * 128 + d0 + 1]; }
        else if (layer == 1) { w0 = gu_w2[col * 64 + d0];   w1v = gu_w2[col * 64 + d0 + 1]; }
        else                 { w0 = att_w1[col * 128 + d0]; w1v = att_w1[col * 128 + d0 + 1]; }
        unsigned h0, l0, h1, l1;
        split2(w0, h0, l0); split2(w1v, h1, l1);
        unsigned lo16 = hl ? l0 : h0;
        unsigned hi16 = hl ? l1 : h1;
        wsu[OFF_BFRAG + i] = lo16 | (hi16 << 16);
    }
    for (int i = t0; i < 4096; i += stride) {
        int d = i >> 6, k = i & 63;
        ws[OFF_AW1BT + i] = att_w1[k * 128 + 64 + d];
    }
    for (int i = t0; i < 384; i += stride) {
        int rr = i >> 6, k = i & 63;
        float a = gu_b1[k];
        for (int d = 0; d < 64; ++d)
            a += gu_w1[k * 128 + 64 + d] * rate_emb[rr * 64 + d];
        ws[OFF_ERC + i] = a;
    }
}

// ---------- prep_w32: composite fragments + ab1c ----------
__global__ __launch_bounds__(256) void prep_w32(const float* __restrict__ att_w1,
                                                const float* __restrict__ gu_w2,
                                                const float* __restrict__ att_b1,
                                                const float* __restrict__ gu_b2,
                                                float* __restrict__ ws) {
    unsigned* w32f = (unsigned*)ws + OFF_W32F;
    int i = blockIdx.x * 256 + threadIdx.x;   // 16 blocks x 256 = 4096
    {
        int frag = i >> 8, within = i & 255, lane = within >> 2, r = within & 3;
        int hl = frag & 1, ct = (frag >> 1) & 3, kt = frag >> 3;
        int col = ct * 16 + (lane & 15);
        int d0 = kt * 32 + 8 * (lane >> 4) + 2 * r;
        if (hl == 0) {
            float w0 = 0.f, w1v = 0.f;
            for (int k2 = 0; k2 < 64; ++k2) {
                float a = att_w1[col * 128 + k2];
                w0  = fmaf(a, gu_w2[k2 * 64 + d0],     w0);
                w1v = fmaf(a, gu_w2[k2 * 64 + d0 + 1], w1v);
            }
            w32f[i] = packbf(w0, w1v);
        } else {
            w32f[i] = 0u;
        }
    }
    if (blockIdx.x == 0 && threadIdx.x < 64) {
        int k3 = threadIdx.x;
        float a = att_b1[k3];
        for (int k2 = 0; k2 < 64; ++k2)
            a = fmaf(att_w1[k3 * 128 + k2], gu_b2[k2], a);
        ws[OFF_AB1C + k3] = a;
    }
}

__global__ void prep2_qc(const int* __restrict__ iids, const float* __restrict__ item_emb,
                         const float* __restrict__ ws, float* __restrict__ qc) {
    int b = blockIdx.x, k = threadIdx.x;
    int iid = iids[b];
    const float* awbT = ws + OFF_AW1BT;
    const float* irow = item_emb + (size_t)iid * 64;
    float acc = 0.f;
    for (int d = 0; d < 64; ++d)
        acc = fmaf(awbT[d * 64 + k], irow[d], acc);
    qc[b * 64 + k] = acc;
}

#define LAYER_MFMA(LAYER_ID, ACC, AHARR, BFRAG, LANE)                            \
    _Pragma("unroll")                                                            \
    for (int ct = 0; ct < 4; ++ct) {                                             \
        const unsigned* fb = &BFRAG[((((LAYER_ID) * 2 + 0) * 4 + ct) * 2) * 256 + LANE * 4]; \
        u32x4 bh0 = *(const u32x4*)(fb + 0 * 256);                               \
        u32x4 bh1 = *(const u32x4*)(fb + 8 * 256);                               \
        ACC[ct] = __builtin_amdgcn_mfma_f32_16x16x32_bf16(AHARR[0], __builtin_bit_cast(bf16x8, bh0), ACC[ct], 0, 0, 0); \
        ACC[ct] = __builtin_amdgcn_mfma_f32_16x16x32_bf16(AHARR[1], __builtin_bit_cast(bf16x8, bh1), ACC[ct], 0, 0, 0); \
    }

// ---------- prep_h1u (r17-proven) ----------
__global__ __launch_bounds__(64) void prep_h1u(const float* __restrict__ user_emb,
                                               const float* __restrict__ ws,
                                               float* __restrict__ h1u) {
    __shared__ __align__(16) __bf16 XH[16 * 64];
    const int blk = blockIdx.x;
    const int lane = threadIdx.x;
    const int lrow = lane & 15;
    const int lgrp = lane >> 4;
    const int lcol = lane & 15;
    const unsigned* __restrict__ bfrag = (const unsigned*)ws + OFF_BFRAG;
    {
        const int dq = lane & 15;
        const int rowt = lane >> 4;
#pragma unroll
        for (int p = 0; p < 4; ++p) {
            int lr = p * 4 + rowt;
            int u  = blk * 16 + lr;
            float4 v = *(const float4*)(user_emb + (size_t)u * 64 + dq * 4);
            bf16x4 hv = { (__bf16)v.x, (__bf16)v.y, (__bf16)v.z, (__bf16)v.w };
            int g = dq >> 1;
            int idx = lr * 64 + ((g ^ (lr & 7)) << 3) + (dq & 1) * 4;
            *(bf16x4*)&XH[idx] = hv;
        }
    }
    bf16x8 AH[2];
    {
        int s = lrow & 7;
#pragma unroll
        for (int kt = 0; kt < 2; ++kt)
            AH[kt] = *(const bf16x8*)&XH[lrow * 64 + (((kt * 4 + lgrp) ^ s) << 3)];
    }
    f32x4 acc[4];
#pragma unroll
    for (int ct = 0; ct < 4; ++ct)
#pragma unroll
        for (int r = 0; r < 4; ++r) acc[ct][r] = 0.f;
    LAYER_MFMA(0, acc, AH, bfrag, lane)
#pragma unroll
    for (int ct = 0; ct < 4; ++ct)
#pragma unroll
        for (int r = 0; r < 4; ++r)
            h1u[(size_t)(blk * 16 + lgrp * 4 + r) * 64 + ct * 16 + lcol] = acc[ct][r];
}

// ---------- fused v4: 2 tiles/wave, ZERO LDS, composite W32 ----------
// Tables read per-lane directly from global (L2-hot broadcast); masks from
// direct pad loads; erc from ws as float4. Straight-line tile bodies (r8
// lesson: loops over the body => catastrophic spill). Single atomic set.
__global__ __launch_bounds__(64) void fused_main4(
    const int* __restrict__ pad, const float* __restrict__ h1u,
    const float* __restrict__ gu_b2, const float* __restrict__ att_w2,
    const float* __restrict__ att_b2,
    const float* __restrict__ ws, float* __restrict__ aggbuf, float* __restrict__ scbuf) {

    const unsigned id = blockIdx.x;     // < B_SZ*7
    const int b = id / 7;
    const int c = id - b * 7;           // chunk: tiles 2c, 2c+1 (c=6: tile 12 only)
    const int lane = threadIdx.x;
    const int lrow = lane & 15;
    const int lgrp = lane >> 4;
    const int lcol = lane & 15;
    const unsigned* __restrict__ bfrag = (const unsigned*)ws + OFF_BFRAG;
    const unsigned* __restrict__ w32f  = (const unsigned*)ws + OFF_W32F;
    const float* __restrict__ ercp = ws + OFF_ERC;
    const float ab2 = att_b2[0];

    // per-lane table registers (L2-hot broadcast loads, no LDS)
    float b2v[4], aw2v[4], a1cv[4], qcv[4];
#pragma unroll
    for (int ct = 0; ct < 4; ++ct) {
        int k = ct * 16 + lcol;
        b2v[ct]  = gu_b2[k];
        aw2v[ct] = att_w2[k];
        a1cv[ct] = ws[OFF_AB1C + k];
        qcv[ct]  = ws[OFF_QC + b * 64 + k];
    }

    float aggr[4] = { 0.f, 0.f, 0.f, 0.f };
    float swave = 0.f;

#define TILE_BODY(TT)                                                            \
    {                                                                            \
        const int n = (TT) * 16 + lrow;                                          \
        const bool valid = (n < N_SZ);                                           \
        int uid = 0, rid = 0;                                                    \
        if (valid) {                                                             \
            int2 pr = ((const int2*)pad)[b * N_SZ + n];                          \
            uid = pr.x; rid = pr.y;                                              \
        }                                                                        \
        float maskr[4];                                                          \
        _Pragma("unroll")                                                        \
        for (int r = 0; r < 4; ++r) {                                            \
            int nr = (TT) * 16 + lgrp * 4 + r;                                   \
            int uidr = (nr < N_SZ) ? pad[2 * (b * N_SZ + nr)] : 0;               \
            maskr[r] = (nr < N_SZ && uidr > 0) ? 1.f : 0.f;                      \
        }                                                                        \
        bf16x8 AH[2];                                                            \
        _Pragma("unroll")                                                        \
        for (int kt = 0; kt < 2; ++kt) {                                         \
            const int ko = kt * 32 + lgrp * 8;                                   \
            float4 a = make_float4(0.f, 0.f, 0.f, 0.f), cc = a;                  \
            if (valid) {                                                         \
                const float* hp = h1u + (size_t)uid * 64 + ko;                   \
                a  = *(const float4*)hp;                                         \
                cc = *(const float4*)(hp + 4);                                   \
            }                                                                    \
            float4 ea = *(const float4*)&ercp[rid * 64 + ko];                    \
            float4 ec = *(const float4*)&ercp[rid * 64 + ko + 4];                \
            float h0 = fmaxf(a.x + ea.x, 0.f), h1 = fmaxf(a.y + ea.y, 0.f);      \
            float h2 = fmaxf(a.z + ea.z, 0.f), h3 = fmaxf(a.w + ea.w, 0.f);      \
            float h4 = fmaxf(cc.x + ec.x, 0.f), h5 = fmaxf(cc.y + ec.y, 0.f);    \
            float h6 = fmaxf(cc.z + ec.z, 0.f), h7 = fmaxf(cc.w + ec.w, 0.f);    \
            u32x4 hq = { packbf(h0, h1), packbf(h2, h3),                         \
                         packbf(h4, h5), packbf(h6, h7) };                       \
            AH[kt] = __builtin_bit_cast(bf16x8, hq);                             \
        }                                                                        \
        f32x4 f_reg[4];                                                          \
        _Pragma("unroll")                                                        \
        for (int ct = 0; ct < 4; ++ct) {                                         \
            _Pragma("unroll")                                                    \
            for (int r = 0; r < 4; ++r) f_reg[ct][r] = b2v[ct];                  \
        }                                                                        \
        LAYER_MFMA(1, f_reg, AH, bfrag, lane)                                    \
        f32x4 acc3[4];                                                           \
        _Pragma("unroll")                                                        \
        for (int ct = 0; ct < 4; ++ct) {                                         \
            _Pragma("unroll")                                                    \
            for (int r = 0; r < 4; ++r)                                          \
                acc3[ct][r] = fmaf(maskr[r], qcv[ct], a1cv[ct]);                 \
        }                                                                        \
        LAYER_MFMA(0, acc3, AH, w32f, lane)                                      \
        float pm[4] = { 0.f, 0.f, 0.f, 0.f };                                    \
        _Pragma("unroll")                                                        \
        for (int ct = 0; ct < 4; ++ct) {                                         \
            _Pragma("unroll")                                                    \
            for (int r = 0; r < 4; ++r)                                          \
                pm[r] = fmaf(fmaxf(acc3[ct][r], 0.f), aw2v[ct], pm[r]);          \
        }                                                                        \
        _Pragma("unroll")                                                        \
        for (int off = 1; off <= 8; off <<= 1) {                                 \
            _Pragma("unroll")                                                    \
            for (int r = 0; r < 4; ++r) pm[r] += __shfl_xor(pm[r], off);         \
        }                                                                        \
        float miur[4];                                                           \
        _Pragma("unroll")                                                        \
        for (int r = 0; r < 4; ++r) {                                            \
            miur[r] = __expf(pm[r] + ab2) * maskr[r];                            \
            swave += miur[r];                                                    \
        }                                                                        \
        _Pragma("unroll")                                                        \
        for (int ct = 0; ct < 4; ++ct) {                                         \
            _Pragma("unroll")                                                    \
            for (int r = 0; r < 4; ++r)                                          \
                aggr[ct] = fmaf(miur[r], f_reg[ct][r], aggr[ct]);                \
        }                                                                        \
    }

    TILE_BODY(2 * c)
    if (c < 6) TILE_BODY(2 * c + 1)

    // ---- reduce over lane groups, single atomic set ----
#pragma unroll
    for (int ct = 0; ct < 4; ++ct) {
        float v = aggr[ct];
        v += __shfl_xor(v, 16);
        v += __shfl_xor(v, 32);
        aggr[ct] = v;
    }
    swave += __shfl_xor(swave, 16);
    swave += __shfl_xor(swave, 32);
    if (lane < 16) {
#pragma unroll
        for (int ct = 0; ct < 4; ++ct)
            atomicAdd(&aggbuf[b * 64 + ct * 16 + lane], aggr[ct]);
    }
    if (lane == 0)
        atomicAdd(&scbuf[b], swave);
}

// ---------- fused v1: exact r15 (fallback if ws too small) ----------
__global__ __launch_bounds__(64) void fused_main1(
    const int* __restrict__ pad, const float* __restrict__ user_emb,
    const float* __restrict__ gu_b2, const float* __restrict__ att_b1,
    const float* __restrict__ att_w2, const float* __restrict__ att_b2,
    const float* __restrict__ ws, float* __restrict__ aggbuf, float* __restrict__ scbuf) {

    __shared__ __align__(16) __bf16 XH[16 * 64];
    __shared__ float erc_s[6 * 65];
    __shared__ int   rid_s[16];
    __shared__ float mask_s[16];
    __shared__ float b2_s[64], aw2_s[64], ab1_s[64], qc_s[64];

    const unsigned id = blockIdx.x;
    const int b = id / 13;
    const int t = id - b * 13;
    const int lane = threadIdx.x;
    const int lrow = lane & 15;
    const int lgrp = lane >> 4;
    const int lcol = lane & 15;
    const unsigned* __restrict__ bfrag = (const unsigned*)ws + OFF_BFRAG;
    const float ab2 = att_b2[0];

    b2_s[lane]  = gu_b2[lane];
    aw2_s[lane] = att_w2[lane];
    ab1_s[lane] = att_b1[lane];
    qc_s[lane]  = ws[OFF_QC + b * 64 + lane];
#pragma unroll
    for (int i = 0; i < 6; ++i) {
        int j = i * 64 + lane;
        erc_s[(j >> 6) * 65 + (j & 63)] = ws[OFF_ERC + j];
    }
    {
        const int dq = lane & 15;
        const int rowt = lane >> 4;
#pragma unroll
        for (int p = 0; p < 4; ++p) {
            int lr = p * 4 + rowt;
            int n  = t * 16 + lr;
            int uid = 0, rid = 0;
            float4 v = make_float4(0.f, 0.f, 0.f, 0.f);
            if (n < N_SZ) {
                int2 pr = ((const int2*)pad)[b * N_SZ + n];
                uid = pr.x; rid = pr.y;
                v = *(const float4*)(user_emb + (size_t)uid * 64 + dq * 4);
            }
            bf16x4 hv = { (__bf16)v.x, (__bf16)v.y, (__bf16)v.z, (__bf16)v.w };
            int g = dq >> 1;
            int idx = lr * 64 + ((g ^ (lr & 7)) << 3) + (dq & 1) * 4;
            *(bf16x4*)&XH[idx] = hv;
            if (dq == 0) {
                rid_s[lr]  = (n < N_SZ) ? rid : 0;
                mask_s[lr] = (n < N_SZ && uid > 0) ? 1.f : 0.f;
            }
        }
    }
    auto loadA = [&](bf16x8 A[2]) {
        int s = lrow & 7;
#pragma unroll
        for (int kt = 0; kt < 2; ++kt)
            A[kt] = *(const bf16x8*)&XH[lrow * 64 + (((kt * 4 + lgrp) ^ s) << 3)];
    };
    {
        bf16x8 AH[2];
        loadA(AH);
        int ridr[4];
#pragma unroll
        for (int r = 0; r < 4; ++r) ridr[r] = rid_s[lgrp * 4 + r];
        f32x4 acc[4];
#pragma unroll
        for (int ct = 0; ct < 4; ++ct) {
            int k = ct * 16 + lcol;
#pragma unroll
            for (int r = 0; r < 4; ++r) acc[ct][r] = erc_s[ridr[r] * 65 + k];
        }
        LAYER_MFMA(0, acc, AH, bfrag, lane)
#pragma unroll
        for (int ct = 0; ct < 4; ++ct) {
            int col = ct * 16 + lcol;
#pragma unroll
            for (int r = 0; r < 4; ++r) {
                float hv = fmaxf(acc[ct][r], 0.f);
                int ln = lgrp * 4 + r;
                int idx = ln * 64 + (((col >> 3) ^ (ln & 7)) << 3) + (col & 7);
                XH[idx] = (__bf16)hv;
            }
        }
    }
    f32x4 f_reg[4];
    {
        bf16x8 AH[2];
        loadA(AH);
#pragma unroll
        for (int ct = 0; ct < 4; ++ct) {
            float bb = b2_s[ct * 16 + lcol];
#pragma unroll
            for (int r = 0; r < 4; ++r) f_reg[ct][r] = bb;
        }
        LAYER_MFMA(1, f_reg, AH, bfrag, lane)
#pragma unroll
        for (int ct = 0; ct < 4; ++ct) {
            int col = ct * 16 + lcol;
#pragma unroll
            for (int r = 0; r < 4; ++r) {
                int ln = lgrp * 4 + r;
                int idx = ln * 64 + (((col >> 3) ^ (ln & 7)) << 3) + (col & 7);
                XH[idx] = (__bf16)f_reg[ct][r];
            }
        }
    }
    float aggr[4];
    float swave = 0.f;
    {
        bf16x8 AH[2];
        loadA(AH);
        float maskr[4];
#pragma unroll
        for (int r = 0; r < 4; ++r) maskr[r] = mask_s[lgrp * 4 + r];
        f32x4 acc[4];
#pragma unroll
        for (int ct = 0; ct < 4; ++ct) {
            int k = ct * 16 + lcol;
            float bb = ab1_s[k], qq = qc_s[k];
#pragma unroll
            for (int r = 0; r < 4; ++r) acc[ct][r] = fmaf(maskr[r], qq, bb);
        }
        LAYER_MFMA(2, acc, AH, bfrag, lane)
        float pm[4] = { 0.f, 0.f, 0.f, 0.f };
#pragma unroll
        for (int ct = 0; ct < 4; ++ct) {
            float w2v = aw2_s[ct * 16 + lcol];
#pragma unroll
            for (int r = 0; r < 4; ++r)
                pm[r] = fmaf(fmaxf(acc[ct][r], 0.f), w2v, pm[r]);
        }
#pragma unroll
        for (int off = 1; off <= 8; off <<= 1) {
#pragma unroll
            for (int r = 0; r < 4; ++r) pm[r] += __shfl_xor(pm[r], off);
        }
        float miur[4];
#pragma unroll
        for (int r = 0; r < 4; ++r) {
            miur[r] = __expf(pm[r] + ab2) * maskr[r];
            swave += miur[r];
        }
#pragma unroll
        for (int ct = 0; ct < 4; ++ct) {
            float a = 0.f;
#pragma unroll
            for (int r = 0; r < 4; ++r)
                a = fmaf(miur[r], f_reg[ct][r], a);
            aggr[ct] = a;
        }
    }
#pragma unroll
    for (int ct = 0; ct < 4; ++ct) {
        float v = aggr[ct];
        v += __shfl_xor(v, 16);
        v += __shfl_xor(v, 32);
        aggr[ct] = v;
    }
    swave += __shfl_xor(swave, 16);
    swave += __shfl_xor(swave, 32);
    if (lane < 16) {
#pragma unroll
        for (int ct = 0; ct < 4; ++ct)
            atomicAdd(&aggbuf[b * 64 + ct * 16 + lane], aggr[ct]);
    }
    if (lane == 0)
        atomicAdd(&scbuf[b], swave);
}

// ---- normalize + z = relu(agg @ agg_w^T + agg_b) ----
__global__ __launch_bounds__(256) void final_z(const float* __restrict__ aggbuf,
                                               const float* __restrict__ scbuf,
                                               const float* __restrict__ agg_w,
                                               const float* __restrict__ agg_b,
                                               float* __restrict__ out) {
    __shared__ float aws[64 * 65];
    int t = threadIdx.x;
    for (int idx = t; idx < 4096; idx += 256)
        aws[(idx >> 6) * 65 + (idx & 63)] = agg_w[idx];
    __syncthreads();
    int g = t >> 6, k = t & 63;
    for (int bi = 0; bi < 2; ++bi) {
        int b = blockIdx.x * 8 + g * 2 + bi;
        const float* arow = aggbuf + b * 64;
        float inv = 1.f / (scbuf[b] + 1e-10f);
        float dot = 0.f;
        for (int d = 0; d < 64; ++d)
            dot = fmaf(aws[k * 65 + d], arow[d], dot);
        out[b * 64 + k] = fmaxf(fmaf(inv, dot, agg_b[k]), 0.f);
    }
}

extern "C" void kernel_launch(void* const* d_in, const int* in_sizes, int n_in,
                              void* d_out, int out_size, void* d_ws, size_t ws_size,
                              hipStream_t stream) {
    const int*   iids     = (const int*)d_in[0];
    const int*   pad      = (const int*)d_in[1];
    const float* user_emb = (const float*)d_in[2];
    const float* item_emb = (const float*)d_in[3];
    const float* rate_emb = (const float*)d_in[4];
    const float* gu_w1    = (const float*)d_in[5];
    const float* gu_b1    = (const float*)d_in[6];
    const float* gu_w2    = (const float*)d_in[7];
    const float* gu_b2    = (const float*)d_in[8];
    const float* att_w1   = (const float*)d_in[9];
    const float* att_b1   = (const float*)d_in[10];
    const float* att_w2   = (const float*)d_in[11];
    const float* att_b2   = (const float*)d_in[12];
    const float* agg_w    = (const float*)d_in[13];
    const float* agg_b    = (const float*)d_in[14];
    float* ws  = (float*)d_ws;
    float* out = (float*)d_out;

    hipLaunchKernelGGL(prep1, dim3(32), dim3(256), 0, stream,
                       gu_w1, gu_b1, gu_w2, att_w1, rate_emb, ws);
    hipLaunchKernelGGL(prep2_qc, dim3(B_SZ), dim3(64), 0, stream,
                       iids, item_emb, ws, ws + OFF_QC);
    hipMemsetAsync(ws + OFF_AGG, 0, (size_t)(B_SZ * 64 + B_SZ) * sizeof(float), stream);

    if (ws_size >= WS_NEED_BYTES) {
        hipLaunchKernelGGL(prep_w32, dim3(16), dim3(256), 0, stream,
                           att_w1, gu_w2, att_b1, gu_b2, ws);
        hipLaunchKernelGGL(prep_h1u, dim3(NU_SZ / 16), dim3(64), 0, stream,
                           user_emb, ws, ws + OFF_H1U);
        hipLaunchKernelGGL(fused_main4, dim3(B_SZ * 7), dim3(64), 0, stream,
                           pad, ws + OFF_H1U, gu_b2, att_w2, att_b2,
                           ws, ws + OFF_AGG, ws + OFF_SC);
    } else {
        hipLaunchKernelGGL(fused_main1, dim3(B_SZ * 13), dim3(64), 0, stream,
                           pad, user_emb, gu_b2, att_b1, att_w2, att_b2,
                           ws, ws + OFF_AGG, ws + OFF_SC);
    }
    hipLaunchKernelGGL(final_z, dim3(B_SZ / 8), dim3(256), 0, stream,
                       ws + OFF_AGG, ws + OFF_SC, agg_w, agg_b, out);
}

// Round 20
// 118.644 us; speedup vs baseline: 1.1497x; 1.1497x over previous
//
#include <hip/hip_runtime.h>
#include <hip/hip_bf16.h>

#define B_SZ 4096
#define N_SZ 200
#define NU_SZ 100000

// workspace offsets (4-byte units)
#define OFF_BFRAG 0        // 12288 u32: W-fragments (layers 0..2)
#define OFF_AW1BT 12288    // 4096 f32
#define OFF_ERC   16384    // 384  f32
#define OFF_QC    16768    // B*64 f32
#define OFF_AGG   278912   // B*64 f32 (atomic)
#define OFF_SC    541056   // B f32 (atomic)
#define OFF_W32F  545152   // 4096 u32: composite W32 = AW1a @ W2 fragments (hi rows)
#define OFF_AB1C  549248   // 64 f32: ab1 + AW1a @ b2
#define OFF_H1U   549312   // NU*64 f32
#define WS_NEED_BYTES ((size_t)(OFF_H1U + NU_SZ * 64) * 4)

typedef __attribute__((ext_vector_type(8))) __bf16 bf16x8;
typedef __attribute__((ext_vector_type(4))) __bf16 bf16x4;
typedef __attribute__((ext_vector_type(4))) float f32x4;
typedef __attribute__((ext_vector_type(4))) unsigned u32x4;

__device__ __forceinline__ void split2(float x, unsigned &hi, unsigned &lo) {
    unsigned u = __float_as_uint(x);
    hi = (u + 0x7FFFu + ((u >> 16) & 1u)) >> 16;
    float r = x - __uint_as_float(hi << 16);
    unsigned ul = __float_as_uint(r);
    lo = (ul + 0x7FFFu + ((ul >> 16) & 1u)) >> 16;
}

__device__ __forceinline__ unsigned packbf(float e0, float e1) {
    __bf16 h0 = (__bf16)e0, h1 = (__bf16)e1;
    return ((unsigned)__builtin_bit_cast(unsigned short, h1) << 16) |
           (unsigned)__builtin_bit_cast(unsigned short, h0);
}

// ---------- prep_all: merged prep1 + prep_w32 + ab1c + zero agg/sc ----------
__global__ __launch_bounds__(256) void prep_all(
    const float* __restrict__ gu_w1, const float* __restrict__ gu_b1,
    const float* __restrict__ gu_w2, const float* __restrict__ att_w1,
    const float* __restrict__ att_b1, const float* __restrict__ gu_b2,
    const float* __restrict__ rate_emb, float* __restrict__ ws) {
    const int t0 = blockIdx.x * blockDim.x + threadIdx.x;
    const int stride = blockDim.x * gridDim.x;
    unsigned* wsu = (unsigned*)ws;
    for (int i = t0; i < 12288; i += stride) {
        int frag = i >> 8, within = i & 255, lane = within >> 2, r = within & 3;
        int hl = frag & 1, ct = (frag >> 1) & 3, kt = (frag >> 3) & 1, layer = frag >> 4;
        int col = ct * 16 + (lane & 15);
        int d0 = kt * 32 + 8 * (lane >> 4) + 2 * r;
        float w0, w1v;
        if (layer == 0)      { w0 = gu_w1[col * 128 + d0];  w1v = gu_w1[col * 128 + d0 + 1]; }
        else if (layer == 1) { w0 = gu_w2[col * 64 + d0];   w1v = gu_w2[col * 64 + d0 + 1]; }
        else                 { w0 = att_w1[col * 128 + d0]; w1v = att_w1[col * 128 + d0 + 1]; }
        unsigned h0, l0, h1, l1;
        split2(w0, h0, l0); split2(w1v, h1, l1);
        unsigned lo16 = hl ? l0 : h0;
        unsigned hi16 = hl ? l1 : h1;
        wsu[OFF_BFRAG + i] = lo16 | (hi16 << 16);
    }
    for (int i = t0; i < 4096; i += stride) {
        int d = i >> 6, k = i & 63;
        ws[OFF_AW1BT + i] = att_w1[k * 128 + 64 + d];
    }
    for (int i = t0; i < 384; i += stride) {
        int rr = i >> 6, k = i & 63;
        float a = gu_b1[k];
        for (int d = 0; d < 64; ++d)
            a += gu_w1[k * 128 + 64 + d] * rate_emb[rr * 64 + d];
        ws[OFF_ERC + i] = a;
    }
    for (int i = t0; i < 4096; i += stride) {
        int frag = i >> 8, within = i & 255, lane = within >> 2, r = within & 3;
        int hl = frag & 1, ct = (frag >> 1) & 3, kt = frag >> 3;
        int col = ct * 16 + (lane & 15);
        int d0 = kt * 32 + 8 * (lane >> 4) + 2 * r;
        if (hl == 0) {
            float w0 = 0.f, w1v = 0.f;
            for (int k2 = 0; k2 < 64; ++k2) {
                float a = att_w1[col * 128 + k2];
                w0  = fmaf(a, gu_w2[k2 * 64 + d0],     w0);
                w1v = fmaf(a, gu_w2[k2 * 64 + d0 + 1], w1v);
            }
            wsu[OFF_W32F + i] = packbf(w0, w1v);
        } else {
            wsu[OFF_W32F + i] = 0u;
        }
    }
    for (int i = t0; i < 64; i += stride) {
        float a = att_b1[i];
        for (int k2 = 0; k2 < 64; ++k2)
            a = fmaf(att_w1[i * 128 + k2], gu_b2[k2], a);
        ws[OFF_AB1C + i] = a;
    }
    for (int i = t0; i < B_SZ * 64; i += stride) ws[OFF_AGG + i] = 0.f;
    for (int i = t0; i < B_SZ; i += stride)      ws[OFF_SC + i] = 0.f;
}

#define LAYER_MFMA(LAYER_ID, ACC, AHARR, BFRAG, LANE)                            \
    _Pragma("unroll")                                                            \
    for (int ct = 0; ct < 4; ++ct) {                                             \
        const unsigned* fb = &BFRAG[((((LAYER_ID) * 2 + 0) * 4 + ct) * 2) * 256 + LANE * 4]; \
        u32x4 bh0 = *(const u32x4*)(fb + 0 * 256);                               \
        u32x4 bh1 = *(const u32x4*)(fb + 8 * 256);                               \
        ACC[ct] = __builtin_amdgcn_mfma_f32_16x16x32_bf16(AHARR[0], __builtin_bit_cast(bf16x8, bh0), ACC[ct], 0, 0, 0); \
        ACC[ct] = __builtin_amdgcn_mfma_f32_16x16x32_bf16(AHARR[1], __builtin_bit_cast(bf16x8, bh1), ACC[ct], 0, 0, 0); \
    }

// ---------- prep_h1u_qc: blocks <NU/16 compute h1u tile; rest compute qc[b] ----------
// DO_H1U=0 fallback grid runs only qc blocks.
template <int DO_H1U>
__global__ __launch_bounds__(64) void prep_h1u_qc(
    const float* __restrict__ user_emb, const int* __restrict__ iids,
    const float* __restrict__ item_emb, const float* __restrict__ ws,
    float* __restrict__ h1u, float* __restrict__ qc) {
    const int blk = blockIdx.x;
    const int lane = threadIdx.x;
    const int nh = DO_H1U ? (NU_SZ / 16) : 0;
    if (blk >= nh) {
        int b = blk - nh;
        int iid = iids[b];
        const float* awbT = ws + OFF_AW1BT;
        const float* irow = item_emb + (size_t)iid * 64;
        float acc = 0.f;
        for (int d = 0; d < 64; ++d)
            acc = fmaf(awbT[d * 64 + lane], irow[d], acc);
        qc[b * 64 + lane] = acc;
        return;
    }
    __shared__ __align__(16) __bf16 XH[16 * 64];
    const int lrow = lane & 15;
    const int lgrp = lane >> 4;
    const int lcol = lane & 15;
    const unsigned* __restrict__ bfrag = (const unsigned*)ws + OFF_BFRAG;
    {
        const int dq = lane & 15;
        const int rowt = lane >> 4;
#pragma unroll
        for (int p = 0; p < 4; ++p) {
            int lr = p * 4 + rowt;
            int u  = blk * 16 + lr;
            float4 v = *(const float4*)(user_emb + (size_t)u * 64 + dq * 4);
            bf16x4 hv = { (__bf16)v.x, (__bf16)v.y, (__bf16)v.z, (__bf16)v.w };
            int g = dq >> 1;
            int idx = lr * 64 + ((g ^ (lr & 7)) << 3) + (dq & 1) * 4;
            *(bf16x4*)&XH[idx] = hv;
        }
    }
    bf16x8 AH[2];
    {
        int s = lrow & 7;
#pragma unroll
        for (int kt = 0; kt < 2; ++kt)
            AH[kt] = *(const bf16x8*)&XH[lrow * 64 + (((kt * 4 + lgrp) ^ s) << 3)];
    }
    f32x4 acc[4];
#pragma unroll
    for (int ct = 0; ct < 4; ++ct)
#pragma unroll
        for (int r = 0; r < 4; ++r) acc[ct][r] = 0.f;
    LAYER_MFMA(0, acc, AH, bfrag, lane)
#pragma unroll
    for (int ct = 0; ct < 4; ++ct)
#pragma unroll
        for (int r = 0; r < 4; ++r)
            h1u[(size_t)(blk * 16 + lgrp * 4 + r) * 64 + ct * 16 + lcol] = acc[ct][r];
}

// ---------- fused v5: single tile, ZERO LDS, composite W32 ----------
__global__ __launch_bounds__(64) void fused_main5(
    const int* __restrict__ pad, const float* __restrict__ h1u,
    const float* __restrict__ gu_b2, const float* __restrict__ att_w2,
    const float* __restrict__ att_b2,
    const float* __restrict__ ws, float* __restrict__ aggbuf, float* __restrict__ scbuf) {

    const unsigned id = blockIdx.x;     // < B_SZ*13
    const int b = id / 13;
    const int t = id - b * 13;
    const int lane = threadIdx.x;
    const int lrow = lane & 15;
    const int lgrp = lane >> 4;
    const int lcol = lane & 15;
    const unsigned* __restrict__ bfrag = (const unsigned*)ws + OFF_BFRAG;
    const unsigned* __restrict__ w32f  = (const unsigned*)ws + OFF_W32F;
    const float* __restrict__ ercp = ws + OFF_ERC;
    const float ab2 = att_b2[0];

    float b2v[4], aw2v[4], a1cv[4], qcv[4];
#pragma unroll
    for (int ct = 0; ct < 4; ++ct) {
        int k = ct * 16 + lcol;
        b2v[ct]  = gu_b2[k];
        aw2v[ct] = att_w2[k];
        a1cv[ct] = ws[OFF_AB1C + k];
        qcv[ct]  = ws[OFF_QC + b * 64 + k];
    }

    const int n = t * 16 + lrow;
    const bool valid = (n < N_SZ);
    int uid = 0, rid = 0;
    if (valid) {
        int2 pr = ((const int2*)pad)[b * N_SZ + n];
        uid = pr.x; rid = pr.y;
    }
    float maskr[4];
#pragma unroll
    for (int r = 0; r < 4; ++r) {
        int nr = t * 16 + lgrp * 4 + r;
        int uidr = (nr < N_SZ) ? pad[2 * (b * N_SZ + nr)] : 0;
        maskr[r] = (nr < N_SZ && uidr > 0) ? 1.f : 0.f;
    }

    bf16x8 AH[2];
#pragma unroll
    for (int kt = 0; kt < 2; ++kt) {
        const int ko = kt * 32 + lgrp * 8;
        float4 a = make_float4(0.f, 0.f, 0.f, 0.f), cc = a;
        if (valid) {
            const float* hp = h1u + (size_t)uid * 64 + ko;
            a  = *(const float4*)hp;
            cc = *(const float4*)(hp + 4);
        }
        float4 ea = *(const float4*)&ercp[rid * 64 + ko];
        float4 ec = *(const float4*)&ercp[rid * 64 + ko + 4];
        float h0 = fmaxf(a.x + ea.x, 0.f), h1 = fmaxf(a.y + ea.y, 0.f);
        float h2 = fmaxf(a.z + ea.z, 0.f), h3 = fmaxf(a.w + ea.w, 0.f);
        float h4 = fmaxf(cc.x + ec.x, 0.f), h5 = fmaxf(cc.y + ec.y, 0.f);
        float h6 = fmaxf(cc.z + ec.z, 0.f), h7 = fmaxf(cc.w + ec.w, 0.f);
        u32x4 hq = { packbf(h0, h1), packbf(h2, h3), packbf(h4, h5), packbf(h6, h7) };
        AH[kt] = __builtin_bit_cast(bf16x8, hq);
    }

    f32x4 f_reg[4];
#pragma unroll
    for (int ct = 0; ct < 4; ++ct) {
#pragma unroll
        for (int r = 0; r < 4; ++r) f_reg[ct][r] = b2v[ct];
    }
    LAYER_MFMA(1, f_reg, AH, bfrag, lane)

    f32x4 acc3[4];
#pragma unroll
    for (int ct = 0; ct < 4; ++ct) {
#pragma unroll
        for (int r = 0; r < 4; ++r)
            acc3[ct][r] = fmaf(maskr[r], qcv[ct], a1cv[ct]);
    }
    LAYER_MFMA(0, acc3, AH, w32f, lane)

    float pm[4] = { 0.f, 0.f, 0.f, 0.f };
#pragma unroll
    for (int ct = 0; ct < 4; ++ct) {
#pragma unroll
        for (int r = 0; r < 4; ++r)
            pm[r] = fmaf(fmaxf(acc3[ct][r], 0.f), aw2v[ct], pm[r]);
    }
#pragma unroll
    for (int off = 1; off <= 8; off <<= 1) {
#pragma unroll
        for (int r = 0; r < 4; ++r) pm[r] += __shfl_xor(pm[r], off);
    }
    float aggr[4];
    float swave = 0.f;
    {
        float miur[4];
#pragma unroll
        for (int r = 0; r < 4; ++r) {
            miur[r] = __expf(pm[r] + ab2) * maskr[r];
            swave += miur[r];
        }
#pragma unroll
        for (int ct = 0; ct < 4; ++ct) {
            float a = 0.f;
#pragma unroll
            for (int r = 0; r < 4; ++r)
                a = fmaf(miur[r], f_reg[ct][r], a);
            aggr[ct] = a;
        }
    }

#pragma unroll
    for (int ct = 0; ct < 4; ++ct) {
        float v = aggr[ct];
        v += __shfl_xor(v, 16);
        v += __shfl_xor(v, 32);
        aggr[ct] = v;
    }
    swave += __shfl_xor(swave, 16);
    swave += __shfl_xor(swave, 32);
    if (lane < 16) {
#pragma unroll
        for (int ct = 0; ct < 4; ++ct)
            atomicAdd(&aggbuf[b * 64 + ct * 16 + lane], aggr[ct]);
    }
    if (lane == 0)
        atomicAdd(&scbuf[b], swave);
}

// ---------- fused v1 fallback (r15-style) ----------
__global__ __launch_bounds__(64) void fused_main1(
    const int* __restrict__ pad, const float* __restrict__ user_emb,
    const float* __restrict__ gu_b2, const float* __restrict__ att_b1,
    const float* __restrict__ att_w2, const float* __restrict__ att_b2,
    const float* __restrict__ ws, float* __restrict__ aggbuf, float* __restrict__ scbuf) {

    __shared__ __align__(16) __bf16 XH[16 * 64];
    __shared__ float erc_s[6 * 65];
    __shared__ int   rid_s[16];
    __shared__ float mask_s[16];
    __shared__ float b2_s[64], aw2_s[64], ab1_s[64], qc_s[64];

    const unsigned id = blockIdx.x;
    const int b = id / 13;
    const int t = id - b * 13;
    const int lane = threadIdx.x;
    const int lrow = lane & 15;
    const int lgrp = lane >> 4;
    const int lcol = lane & 15;
    const unsigned* __restrict__ bfrag = (const unsigned*)ws + OFF_BFRAG;
    const float ab2 = att_b2[0];

    b2_s[lane]  = gu_b2[lane];
    aw2_s[lane] = att_w2[lane];
    ab1_s[lane] = att_b1[lane];
    qc_s[lane]  = ws[OFF_QC + b * 64 + lane];
#pragma unroll
    for (int i = 0; i < 6; ++i) {
        int j = i * 64 + lane;
        erc_s[(j >> 6) * 65 + (j & 63)] = ws[OFF_ERC + j];
    }
    {
        const int dq = lane & 15;
        const int rowt = lane >> 4;
#pragma unroll
        for (int p = 0; p < 4; ++p) {
            int lr = p * 4 + rowt;
            int n  = t * 16 + lr;
            int uid = 0, rid = 0;
            float4 v = make_float4(0.f, 0.f, 0.f, 0.f);
            if (n < N_SZ) {
                int2 pr = ((const int2*)pad)[b * N_SZ + n];
                uid = pr.x; rid = pr.y;
                v = *(const float4*)(user_emb + (size_t)uid * 64 + dq * 4);
            }
            bf16x4 hv = { (__bf16)v.x, (__bf16)v.y, (__bf16)v.z, (__bf16)v.w };
            int g = dq >> 1;
            int idx = lr * 64 + ((g ^ (lr & 7)) << 3) + (dq & 1) * 4;
            *(bf16x4*)&XH[idx] = hv;
            if (dq == 0) {
                rid_s[lr]  = (n < N_SZ) ? rid : 0;
                mask_s[lr] = (n < N_SZ && uid > 0) ? 1.f : 0.f;
            }
        }
    }
    auto loadA = [&](bf16x8 A[2]) {
        int s = lrow & 7;
#pragma unroll
        for (int kt = 0; kt < 2; ++kt)
            A[kt] = *(const bf16x8*)&XH[lrow * 64 + (((kt * 4 + lgrp) ^ s) << 3)];
    };
    {
        bf16x8 AH[2];
        loadA(AH);
        int ridr[4];
#pragma unroll
        for (int r = 0; r < 4; ++r) ridr[r] = rid_s[lgrp * 4 + r];
        f32x4 acc[4];
#pragma unroll
        for (int ct = 0; ct < 4; ++ct) {
            int k = ct * 16 + lcol;
#pragma unroll
            for (int r = 0; r < 4; ++r) acc[ct][r] = erc_s[ridr[r] * 65 + k];
        }
        LAYER_MFMA(0, acc, AH, bfrag, lane)
#pragma unroll
        for (int ct = 0; ct < 4; ++ct) {
            int col = ct * 16 + lcol;
#pragma unroll
            for (int r = 0; r < 4; ++r) {
                float hv = fmaxf(acc[ct][r], 0.f);
                int ln = lgrp * 4 + r;
                int idx = ln * 64 + (((col >> 3) ^ (ln & 7)) << 3) + (col & 7);
                XH[idx] = (__bf16)hv;
            }
        }
    }
    f32x4 f_reg[4];
    {
        bf16x8 AH[2];
        loadA(AH);
#pragma unroll
        for (int ct = 0; ct < 4; ++ct) {
            float bb = b2_s[ct * 16 + lcol];
#pragma unroll
            for (int r = 0; r < 4; ++r) f_reg[ct][r] = bb;
        }
        LAYER_MFMA(1, f_reg, AH, bfrag, lane)
#pragma unroll
        for (int ct = 0; ct < 4; ++ct) {
            int col = ct * 16 + lcol;
#pragma unroll
            for (int r = 0; r < 4; ++r) {
                int ln = lgrp * 4 + r;
                int idx = ln * 64 + (((col >> 3) ^ (ln & 7)) << 3) + (col & 7);
                XH[idx] = (__bf16)f_reg[ct][r];
            }
        }
    }
    float aggr[4];
    float swave = 0.f;
    {
        bf16x8 AH[2];
        loadA(AH);
        float maskr[4];
#pragma unroll
        for (int r = 0; r < 4; ++r) maskr[r] = mask_s[lgrp * 4 + r];
        f32x4 acc[4];
#pragma unroll
        for (int ct = 0; ct < 4; ++ct) {
            int k = ct * 16 + lcol;
            float bb = ab1_s[k], qq = qc_s[k];
#pragma unroll
            for (int r = 0; r < 4; ++r) acc[ct][r] = fmaf(maskr[r], qq, bb);
        }
        LAYER_MFMA(2, acc, AH, bfrag, lane)
        float pm[4] = { 0.f, 0.f, 0.f, 0.f };
#pragma unroll
        for (int ct = 0; ct < 4; ++ct) {
            float w2v = aw2_s[ct * 16 + lcol];
#pragma unroll
            for (int r = 0; r < 4; ++r)
                pm[r] = fmaf(fmaxf(acc[ct][r], 0.f), w2v, pm[r]);
        }
#pragma unroll
        for (int off = 1; off <= 8; off <<= 1) {
#pragma unroll
            for (int r = 0; r < 4; ++r) pm[r] += __shfl_xor(pm[r], off);
        }
        float miur[4];
#pragma unroll
        for (int r = 0; r < 4; ++r) {
            miur[r] = __expf(pm[r] + ab2) * maskr[r];
            swave += miur[r];
        }
#pragma unroll
        for (int ct = 0; ct < 4; ++ct) {
            float a = 0.f;
#pragma unroll
            for (int r = 0; r < 4; ++r)
                a = fmaf(miur[r], f_reg[ct][r], a);
            aggr[ct] = a;
        }
    }
#pragma unroll
    for (int ct = 0; ct < 4; ++ct) {
        float v = aggr[ct];
        v += __shfl_xor(v, 16);
        v += __shfl_xor(v, 32);
        aggr[ct] = v;
    }
    swave += __shfl_xor(swave, 16);
    swave += __shfl_xor(swave, 32);
    if (lane < 16) {
#pragma unroll
        for (int ct = 0; ct < 4; ++ct)
            atomicAdd(&aggbuf[b * 64 + ct * 16 + lane], aggr[ct]);
    }
    if (lane == 0)
        atomicAdd(&scbuf[b], swave);
}

// ---- normalize + z = relu(agg @ agg_w^T + agg_b) ----
__global__ __launch_bounds__(256) void final_z(const float* __restrict__ aggbuf,
                                               const float* __restrict__ scbuf,
                                               const float* __restrict__ agg_w,
                                               const float* __restrict__ agg_b,
                                               float* __restrict__ out) {
    __shared__ float aws[64 * 65];
    int t = threadIdx.x;
    for (int idx = t; idx < 4096; idx += 256)
        aws[(idx >> 6) * 65 + (idx & 63)] = agg_w[idx];
    __syncthreads();
    int g = t >> 6, k = t & 63;
    for (int bi = 0; bi < 2; ++bi) {
        int b = blockIdx.x * 8 + g * 2 + bi;
        const float* arow = aggbuf + b * 64;
        float inv = 1.f / (scbuf[b] + 1e-10f);
        float dot = 0.f;
        for (int d = 0; d < 64; ++d)
            dot = fmaf(aws[k * 65 + d], arow[d], dot);
        out[b * 64 + k] = fmaxf(fmaf(inv, dot, agg_b[k]), 0.f);
    }
}

extern "C" void kernel_launch(void* const* d_in, const int* in_sizes, int n_in,
                              void* d_out, int out_size, void* d_ws, size_t ws_size,
                              hipStream_t stream) {
    const int*   iids     = (const int*)d_in[0];
    const int*   pad      = (const int*)d_in[1];
    const float* user_emb = (const float*)d_in[2];
    const float* item_emb = (const float*)d_in[3];
    const float* rate_emb = (const float*)d_in[4];
    const float* gu_w1    = (const float*)d_in[5];
    const float* gu_b1    = (const float*)d_in[6];
    const float* gu_w2    = (const float*)d_in[7];
    const float* gu_b2    = (const float*)d_in[8];
    const float* att_w1   = (const float*)d_in[9];
    const float* att_b1   = (const float*)d_in[10];
    const float* att_w2   = (const float*)d_in[11];
    const float* att_b2   = (const float*)d_in[12];
    const float* agg_w    = (const float*)d_in[13];
    const float* agg_b    = (const float*)d_in[14];
    float* ws  = (float*)d_ws;
    float* out = (float*)d_out;

    hipLaunchKernelGGL(prep_all, dim3(64), dim3(256), 0, stream,
                       gu_w1, gu_b1, gu_w2, att_w1, att_b1, gu_b2, rate_emb, ws);

    if (ws_size >= WS_NEED_BYTES) {
        hipLaunchKernelGGL((prep_h1u_qc<1>), dim3(NU_SZ / 16 + B_SZ), dim3(64), 0, stream,
                           user_emb, iids, item_emb, ws, ws + OFF_H1U, ws + OFF_QC);
        hipLaunchKernelGGL(fused_main5, dim3(B_SZ * 13), dim3(64), 0, stream,
                           pad, ws + OFF_H1U, gu_b2, att_w2, att_b2,
                           ws, ws + OFF_AGG, ws + OFF_SC);
    } else {
        hipLaunchKernelGGL((prep_h1u_qc<0>), dim3(B_SZ), dim3(64), 0, stream,
                           user_emb, iids, item_emb, ws, ws + OFF_QC, ws + OFF_QC);
        hipLaunchKernelGGL(fused_main1, dim3(B_SZ * 13), dim3(64), 0, stream,
                           pad, user_emb, gu_b2, att_b1, att_w2, att_b2,
                           ws, ws + OFF_AGG, ws + OFF_SC);
    }
    hipLaunchKernelGGL(final_z, dim3(B_SZ / 8), dim3(256), 0, stream,
                       ws + OFF_AGG, ws + OFF_SC, agg_w, agg_b, out);
}

// Round 21
// 99.027 us; speedup vs baseline: 1.3775x; 1.1981x over previous
//
#include <hip/hip_runtime.h>
#include <hip/hip_bf16.h>

#define B_SZ 4096
#define N_SZ 200
#define NU_SZ 100000

// workspace offsets (4-byte units)
#define OFF_BFRAG 0        // 12288 u32: W-fragments (layers 0..2)
#define OFF_AW1BT 12288    // 4096 f32
#define OFF_ERC   16384    // 384  f32
#define OFF_QC    16768    // B*64 f32
#define OFF_AGG   278912   // B*64 f32 (atomic)
#define OFF_SC    541056   // B f32 (atomic)
#define OFF_W32F  545152   // 4096 u32: composite W32 = AW1a @ W2 fragments (hi rows)
#define OFF_AB1C  549248   // 64 f32: ab1 + AW1a @ b2
#define OFF_H1U   549312   // NU*64 f32
#define WS_NEED_BYTES ((size_t)(OFF_H1U + NU_SZ * 64) * 4)

typedef __attribute__((ext_vector_type(8))) __bf16 bf16x8;
typedef __attribute__((ext_vector_type(4))) __bf16 bf16x4;
typedef __attribute__((ext_vector_type(4))) float f32x4;
typedef __attribute__((ext_vector_type(4))) unsigned u32x4;

__device__ __forceinline__ void split2(float x, unsigned &hi, unsigned &lo) {
    unsigned u = __float_as_uint(x);
    hi = (u + 0x7FFFu + ((u >> 16) & 1u)) >> 16;
    float r = x - __uint_as_float(hi << 16);
    unsigned ul = __float_as_uint(r);
    lo = (ul + 0x7FFFu + ((ul >> 16) & 1u)) >> 16;
}

__device__ __forceinline__ unsigned packbf(float e0, float e1) {
    __bf16 h0 = (__bf16)e0, h1 = (__bf16)e1;
    return ((unsigned)__builtin_bit_cast(unsigned short, h1) << 16) |
           (unsigned)__builtin_bit_cast(unsigned short, h0);
}

// ---------- prep_all: merged W-frags + AW1BT + erc + W32 + ab1c + zero agg/sc ----------
__global__ __launch_bounds__(256) void prep_all(
    const float* __restrict__ gu_w1, const float* __restrict__ gu_b1,
    const float* __restrict__ gu_w2, const float* __restrict__ att_w1,
    const float* __restrict__ att_b1, const float* __restrict__ gu_b2,
    const float* __restrict__ rate_emb, float* __restrict__ ws) {
    const int t0 = blockIdx.x * blockDim.x + threadIdx.x;
    const int stride = blockDim.x * gridDim.x;
    unsigned* wsu = (unsigned*)ws;
    for (int i = t0; i < 12288; i += stride) {
        int frag = i >> 8, within = i & 255, lane = within >> 2, r = within & 3;
        int hl = frag & 1, ct = (frag >> 1) & 3, kt = (frag >> 3) & 1, layer = frag >> 4;
        int col = ct * 16 + (lane & 15);
        int d0 = kt * 32 + 8 * (lane >> 4) + 2 * r;
        float w0, w1v;
        if (layer == 0)      { w0 = gu_w1[col * 128 + d0];  w1v = gu_w1[col * 128 + d0 + 1]; }
        else if (layer == 1) { w0 = gu_w2[col * 64 + d0];   w1v = gu_w2[col * 64 + d0 + 1]; }
        else                 { w0 = att_w1[col * 128 + d0]; w1v = att_w1[col * 128 + d0 + 1]; }
        unsigned h0, l0, h1, l1;
        split2(w0, h0, l0); split2(w1v, h1, l1);
        unsigned lo16 = hl ? l0 : h0;
        unsigned hi16 = hl ? l1 : h1;
        wsu[OFF_BFRAG + i] = lo16 | (hi16 << 16);
    }
    for (int i = t0; i < 4096; i += stride) {
        int d = i >> 6, k = i & 63;
        ws[OFF_AW1BT + i] = att_w1[k * 128 + 64 + d];
    }
    for (int i = t0; i < 384; i += stride) {
        int rr = i >> 6, k = i & 63;
        float a = gu_b1[k];
        for (int d = 0; d < 64; ++d)
            a += gu_w1[k * 128 + 64 + d] * rate_emb[rr * 64 + d];
        ws[OFF_ERC + i] = a;
    }
    for (int i = t0; i < 4096; i += stride) {
        int frag = i >> 8, within = i & 255, lane = within >> 2, r = within & 3;
        int hl = frag & 1, ct = (frag >> 1) & 3, kt = frag >> 3;
        int col = ct * 16 + (lane & 15);
        int d0 = kt * 32 + 8 * (lane >> 4) + 2 * r;
        if (hl == 0) {
            float w0 = 0.f, w1v = 0.f;
            for (int k2 = 0; k2 < 64; ++k2) {
                float a = att_w1[col * 128 + k2];
                w0  = fmaf(a, gu_w2[k2 * 64 + d0],     w0);
                w1v = fmaf(a, gu_w2[k2 * 64 + d0 + 1], w1v);
            }
            wsu[OFF_W32F + i] = packbf(w0, w1v);
        } else {
            wsu[OFF_W32F + i] = 0u;
        }
    }
    for (int i = t0; i < 64; i += stride) {
        float a = att_b1[i];
        for (int k2 = 0; k2 < 64; ++k2)
            a = fmaf(att_w1[i * 128 + k2], gu_b2[k2], a);
        ws[OFF_AB1C + i] = a;
    }
    for (int i = t0; i < B_SZ * 64; i += stride) ws[OFF_AGG + i] = 0.f;
    for (int i = t0; i < B_SZ; i += stride)      ws[OFF_SC + i] = 0.f;
}

#define LAYER_MFMA(LAYER_ID, ACC, AHARR, BFRAG, LANE)                            \
    _Pragma("unroll")                                                            \
    for (int ct = 0; ct < 4; ++ct) {                                             \
        const unsigned* fb = &BFRAG[((((LAYER_ID) * 2 + 0) * 4 + ct) * 2) * 256 + LANE * 4]; \
        u32x4 bh0 = *(const u32x4*)(fb + 0 * 256);                               \
        u32x4 bh1 = *(const u32x4*)(fb + 8 * 256);                               \
        ACC[ct] = __builtin_amdgcn_mfma_f32_16x16x32_bf16(AHARR[0], __builtin_bit_cast(bf16x8, bh0), ACC[ct], 0, 0, 0); \
        ACC[ct] = __builtin_amdgcn_mfma_f32_16x16x32_bf16(AHARR[1], __builtin_bit_cast(bf16x8, bh1), ACC[ct], 0, 0, 0); \
    }

// ---------- prep_h1u_qc: blocks <NU/16 compute h1u tile; rest compute qc[b] ----------
template <int DO_H1U>
__global__ __launch_bounds__(64) void prep_h1u_qc(
    const float* __restrict__ user_emb, const int* __restrict__ iids,
    const float* __restrict__ item_emb, const float* __restrict__ ws,
    float* __restrict__ h1u, float* __restrict__ qc) {
    const int blk = blockIdx.x;
    const int lane = threadIdx.x;
    const int nh = DO_H1U ? (NU_SZ / 16) : 0;
    if (blk >= nh) {
        int b = blk - nh;
        int iid = iids[b];
        const float* awbT = ws + OFF_AW1BT;
        const float* irow = item_emb + (size_t)iid * 64;
        float acc = 0.f;
        for (int d = 0; d < 64; ++d)
            acc = fmaf(awbT[d * 64 + lane], irow[d], acc);
        qc[b * 64 + lane] = acc;
        return;
    }
    __shared__ __align__(16) __bf16 XH[16 * 64];
    const int lrow = lane & 15;
    const int lgrp = lane >> 4;
    const int lcol = lane & 15;
    const unsigned* __restrict__ bfrag = (const unsigned*)ws + OFF_BFRAG;
    {
        const int dq = lane & 15;
        const int rowt = lane >> 4;
#pragma unroll
        for (int p = 0; p < 4; ++p) {
            int lr = p * 4 + rowt;
            int u  = blk * 16 + lr;
            float4 v = *(const float4*)(user_emb + (size_t)u * 64 + dq * 4);
            bf16x4 hv = { (__bf16)v.x, (__bf16)v.y, (__bf16)v.z, (__bf16)v.w };
            int g = dq >> 1;
            int idx = lr * 64 + ((g ^ (lr & 7)) << 3) + (dq & 1) * 4;
            *(bf16x4*)&XH[idx] = hv;
        }
    }
    bf16x8 AH[2];
    {
        int s = lrow & 7;
#pragma unroll
        for (int kt = 0; kt < 2; ++kt)
            AH[kt] = *(const bf16x8*)&XH[lrow * 64 + (((kt * 4 + lgrp) ^ s) << 3)];
    }
    f32x4 acc[4];
#pragma unroll
    for (int ct = 0; ct < 4; ++ct)
#pragma unroll
        for (int r = 0; r < 4; ++r) acc[ct][r] = 0.f;
    LAYER_MFMA(0, acc, AH, bfrag, lane)
#pragma unroll
    for (int ct = 0; ct < 4; ++ct)
#pragma unroll
        for (int r = 0; r < 4; ++r)
            h1u[(size_t)(blk * 16 + lgrp * 4 + r) * 64 + ct * 16 + lcol] = acc[ct][r];
}

// ---------- fused v3 (r18 verbatim — best measured: 79 us, VGPR 44) ----------
// Small-LDS tables beat zero-LDS per-lane global loads (r20: 97 us) at equal
// occupancy — LDS broadcast reads are off the latency-critical VMEM path.
__global__ __launch_bounds__(64) void fused_main3(
    const int* __restrict__ pad, const float* __restrict__ h1u,
    const float* __restrict__ gu_b2, const float* __restrict__ att_w2,
    const float* __restrict__ att_b2,
    const float* __restrict__ ws, float* __restrict__ aggbuf, float* __restrict__ scbuf) {

    __shared__ float erc_s[6 * 64];
    __shared__ float mask_s[16];
    __shared__ float b2_s[64], aw2_s[64], a1c_s[64], qc_s[64];

    const unsigned id = blockIdx.x;     // < B_SZ*13
    const int b = id / 13;
    const int t = id - b * 13;
    const int lane = threadIdx.x;
    const int lrow = lane & 15;
    const int lgrp = lane >> 4;
    const int lcol = lane & 15;
    const unsigned* __restrict__ bfrag = (const unsigned*)ws + OFF_BFRAG;
    const unsigned* __restrict__ w32f  = (const unsigned*)ws + OFF_W32F;
    const float ab2 = att_b2[0];

    b2_s[lane]  = gu_b2[lane];
    aw2_s[lane] = att_w2[lane];
    a1c_s[lane] = ws[OFF_AB1C + lane];
    qc_s[lane]  = ws[OFF_QC + b * 64 + lane];
#pragma unroll
    for (int i = 0; i < 6; ++i)
        erc_s[i * 64 + lane] = ws[OFF_ERC + i * 64 + lane];

    const int n = t * 16 + lrow;
    const bool valid = (n < N_SZ);
    int uid = 0, rid = 0;
    if (valid) {
        int2 pr = ((const int2*)pad)[b * N_SZ + n];
        uid = pr.x; rid = pr.y;
    }
    if (lane < 16)
        mask_s[lane] = (valid && uid > 0) ? 1.f : 0.f;

    // ---- A-frag built directly: h[lrow][kt*32+lgrp*8+e] = relu(h1u+erc) ----
    bf16x8 AH[2];
#pragma unroll
    for (int kt = 0; kt < 2; ++kt) {
        const int ko = kt * 32 + lgrp * 8;
        float4 a = make_float4(0.f, 0.f, 0.f, 0.f), c = a;
        if (valid) {
            const float* hp = h1u + (size_t)uid * 64 + ko;
            a = *(const float4*)hp;
            c = *(const float4*)(hp + 4);
        }
        float4 ea = *(const float4*)&erc_s[rid * 64 + ko];
        float4 ec = *(const float4*)&erc_s[rid * 64 + ko + 4];
        float h0 = fmaxf(a.x + ea.x, 0.f), h1 = fmaxf(a.y + ea.y, 0.f);
        float h2 = fmaxf(a.z + ea.z, 0.f), h3 = fmaxf(a.w + ea.w, 0.f);
        float h4 = fmaxf(c.x + ec.x, 0.f), h5 = fmaxf(c.y + ec.y, 0.f);
        float h6 = fmaxf(c.z + ec.z, 0.f), h7 = fmaxf(c.w + ec.w, 0.f);
        u32x4 hq = { packbf(h0, h1), packbf(h2, h3), packbf(h4, h5), packbf(h6, h7) };
        AH[kt] = __builtin_bit_cast(bf16x8, hq);
    }

    // ---- layer 2: f = h @ W2^T + b2 (f32 regs, kept exact for agg) ----
    f32x4 f_reg[4];
#pragma unroll
    for (int ct = 0; ct < 4; ++ct) {
        float bb = b2_s[ct * 16 + lcol];
#pragma unroll
        for (int r = 0; r < 4; ++r) f_reg[ct][r] = bb;
    }
    LAYER_MFMA(1, f_reg, AH, bfrag, lane)

    // ---- layer 3 (composite): ah = relu(h @ W32^T + ab1c + mask*qc) ----
    float maskr[4];
#pragma unroll
    for (int r = 0; r < 4; ++r) maskr[r] = mask_s[lgrp * 4 + r];
    f32x4 acc3[4];
#pragma unroll
    for (int ct = 0; ct < 4; ++ct) {
        int k = ct * 16 + lcol;
        float bb = a1c_s[k], qq = qc_s[k];
#pragma unroll
        for (int r = 0; r < 4; ++r) acc3[ct][r] = fmaf(maskr[r], qq, bb);
    }
    LAYER_MFMA(0, acc3, AH, w32f, lane)

    // ---- miu + agg ----
    float pm[4] = { 0.f, 0.f, 0.f, 0.f };
#pragma unroll
    for (int ct = 0; ct < 4; ++ct) {
        float w2v = aw2_s[ct * 16 + lcol];
#pragma unroll
        for (int r = 0; r < 4; ++r)
            pm[r] = fmaf(fmaxf(acc3[ct][r], 0.f), w2v, pm[r]);
    }
#pragma unroll
    for (int off = 1; off <= 8; off <<= 1) {
#pragma unroll
        for (int r = 0; r < 4; ++r) pm[r] += __shfl_xor(pm[r], off);
    }
    float aggr[4];
    float swave = 0.f;
    {
        float miur[4];
#pragma unroll
        for (int r = 0; r < 4; ++r) {
            miur[r] = __expf(pm[r] + ab2) * maskr[r];
            swave += miur[r];
        }
#pragma unroll
        for (int ct = 0; ct < 4; ++ct) {
            float a = 0.f;
#pragma unroll
            for (int r = 0; r < 4; ++r)
                a = fmaf(miur[r], f_reg[ct][r], a);
            aggr[ct] = a;
        }
    }

#pragma unroll
    for (int ct = 0; ct < 4; ++ct) {
        float v = aggr[ct];
        v += __shfl_xor(v, 16);
        v += __shfl_xor(v, 32);
        aggr[ct] = v;
    }
    swave += __shfl_xor(swave, 16);
    swave += __shfl_xor(swave, 32);
    if (lane < 16) {
#pragma unroll
        for (int ct = 0; ct < 4; ++ct)
            atomicAdd(&aggbuf[b * 64 + ct * 16 + lane], aggr[ct]);
    }
    if (lane == 0)
        atomicAdd(&scbuf[b], swave);
}

// ---------- fused v1 fallback (r15-style; independent of h1u/W32) ----------
__global__ __launch_bounds__(64) void fused_main1(
    const int* __restrict__ pad, const float* __restrict__ user_emb,
    const float* __restrict__ gu_b2, const float* __restrict__ att_b1,
    const float* __restrict__ att_w2, const float* __restrict__ att_b2,
    const float* __restrict__ ws, float* __restrict__ aggbuf, float* __restrict__ scbuf) {

    __shared__ __align__(16) __bf16 XH[16 * 64];
    __shared__ float erc_s[6 * 65];
    __shared__ int   rid_s[16];
    __shared__ float mask_s[16];
    __shared__ float b2_s[64], aw2_s[64], ab1_s[64], qc_s[64];

    const unsigned id = blockIdx.x;
    const int b = id / 13;
    const int t = id - b * 13;
    const int lane = threadIdx.x;
    const int lrow = lane & 15;
    const int lgrp = lane >> 4;
    const int lcol = lane & 15;
    const unsigned* __restrict__ bfrag = (const unsigned*)ws + OFF_BFRAG;
    const float ab2 = att_b2[0];

    b2_s[lane]  = gu_b2[lane];
    aw2_s[lane] = att_w2[lane];
    ab1_s[lane] = att_b1[lane];
    qc_s[lane]  = ws[OFF_QC + b * 64 + lane];
#pragma unroll
    for (int i = 0; i < 6; ++i) {
        int j = i * 64 + lane;
        erc_s[(j >> 6) * 65 + (j & 63)] = ws[OFF_ERC + j];
    }
    {
        const int dq = lane & 15;
        const int rowt = lane >> 4;
#pragma unroll
        for (int p = 0; p < 4; ++p) {
            int lr = p * 4 + rowt;
            int n  = t * 16 + lr;
            int uid = 0, rid = 0;
            float4 v = make_float4(0.f, 0.f, 0.f, 0.f);
            if (n < N_SZ) {
                int2 pr = ((const int2*)pad)[b * N_SZ + n];
                uid = pr.x; rid = pr.y;
                v = *(const float4*)(user_emb + (size_t)uid * 64 + dq * 4);
            }
            bf16x4 hv = { (__bf16)v.x, (__bf16)v.y, (__bf16)v.z, (__bf16)v.w };
            int g = dq >> 1;
            int idx = lr * 64 + ((g ^ (lr & 7)) << 3) + (dq & 1) * 4;
            *(bf16x4*)&XH[idx] = hv;
            if (dq == 0) {
                rid_s[lr]  = (n < N_SZ) ? rid : 0;
                mask_s[lr] = (n < N_SZ && uid > 0) ? 1.f : 0.f;
            }
        }
    }
    auto loadA = [&](bf16x8 A[2]) {
        int s = lrow & 7;
#pragma unroll
        for (int kt = 0; kt < 2; ++kt)
            A[kt] = *(const bf16x8*)&XH[lrow * 64 + (((kt * 4 + lgrp) ^ s) << 3)];
    };
    {
        bf16x8 AH[2];
        loadA(AH);
        int ridr[4];
#pragma unroll
        for (int r = 0; r < 4; ++r) ridr[r] = rid_s[lgrp * 4 + r];
        f32x4 acc[4];
#pragma unroll
        for (int ct = 0; ct < 4; ++ct) {
            int k = ct * 16 + lcol;
#pragma unroll
            for (int r = 0; r < 4; ++r) acc[ct][r] = erc_s[ridr[r] * 65 + k];
        }
        LAYER_MFMA(0, acc, AH, bfrag, lane)
#pragma unroll
        for (int ct = 0; ct < 4; ++ct) {
            int col = ct * 16 + lcol;
#pragma unroll
            for (int r = 0; r < 4; ++r) {
                float hv = fmaxf(acc[ct][r], 0.f);
                int ln = lgrp * 4 + r;
                int idx = ln * 64 + (((col >> 3) ^ (ln & 7)) << 3) + (col & 7);
                XH[idx] = (__bf16)hv;
            }
        }
    }
    f32x4 f_reg[4];
    {
        bf16x8 AH[2];
        loadA(AH);
#pragma unroll
        for (int ct = 0; ct < 4; ++ct) {
            float bb = b2_s[ct * 16 + lcol];
#pragma unroll
            for (int r = 0; r < 4; ++r) f_reg[ct][r] = bb;
        }
        LAYER_MFMA(1, f_reg, AH, bfrag, lane)
#pragma unroll
        for (int ct = 0; ct < 4; ++ct) {
            int col = ct * 16 + lcol;
#pragma unroll
            for (int r = 0; r < 4; ++r) {
                int ln = lgrp * 4 + r;
                int idx = ln * 64 + (((col >> 3) ^ (ln & 7)) << 3) + (col & 7);
                XH[idx] = (__bf16)f_reg[ct][r];
            }
        }
    }
    float aggr[4];
    float swave = 0.f;
    {
        bf16x8 AH[2];
        loadA(AH);
        float maskr[4];
#pragma unroll
        for (int r = 0; r < 4; ++r) maskr[r] = mask_s[lgrp * 4 + r];
        f32x4 acc[4];
#pragma unroll
        for (int ct = 0; ct < 4; ++ct) {
            int k = ct * 16 + lcol;
            float bb = ab1_s[k], qq = qc_s[k];
#pragma unroll
            for (int r = 0; r < 4; ++r) acc[ct][r] = fmaf(maskr[r], qq, bb);
        }
        LAYER_MFMA(2, acc, AH, bfrag, lane)
        float pm[4] = { 0.f, 0.f, 0.f, 0.f };
#pragma unroll
        for (int ct = 0; ct < 4; ++ct) {
            float w2v = aw2_s[ct * 16 + lcol];
#pragma unroll
            for (int r = 0; r < 4; ++r)
                pm[r] = fmaf(fmaxf(acc[ct][r], 0.f), w2v, pm[r]);
        }
#pragma unroll
        for (int off = 1; off <= 8; off <<= 1) {
#pragma unroll
            for (int r = 0; r < 4; ++r) pm[r] += __shfl_xor(pm[r], off);
        }
        float miur[4];
#pragma unroll
        for (int r = 0; r < 4; ++r) {
            miur[r] = __expf(pm[r] + ab2) * maskr[r];
            swave += miur[r];
        }
#pragma unroll
        for (int ct = 0; ct < 4; ++ct) {
            float a = 0.f;
#pragma unroll
            for (int r = 0; r < 4; ++r)
                a = fmaf(miur[r], f_reg[ct][r], a);
            aggr[ct] = a;
        }
    }
#pragma unroll
    for (int ct = 0; ct < 4; ++ct) {
        float v = aggr[ct];
        v += __shfl_xor(v, 16);
        v += __shfl_xor(v, 32);
        aggr[ct] = v;
    }
    swave += __shfl_xor(swave, 16);
    swave += __shfl_xor(swave, 32);
    if (lane < 16) {
#pragma unroll
        for (int ct = 0; ct < 4; ++ct)
            atomicAdd(&aggbuf[b * 64 + ct * 16 + lane], aggr[ct]);
    }
    if (lane == 0)
        atomicAdd(&scbuf[b], swave);
}

// ---- normalize + z = relu(agg @ agg_w^T + agg_b) ----
__global__ __launch_bounds__(256) void final_z(const float* __restrict__ aggbuf,
                                               const float* __restrict__ scbuf,
                                               const float* __restrict__ agg_w,
                                               const float* __restrict__ agg_b,
                                               float* __restrict__ out) {
    __shared__ float aws[64 * 65];
    int t = threadIdx.x;
    for (int idx = t; idx < 4096; idx += 256)
        aws[(idx >> 6) * 65 + (idx & 63)] = agg_w[idx];
    __syncthreads();
    int g = t >> 6, k = t & 63;
    for (int bi = 0; bi < 2; ++bi) {
        int b = blockIdx.x * 8 + g * 2 + bi;
        const float* arow = aggbuf + b * 64;
        float inv = 1.f / (scbuf[b] + 1e-10f);
        float dot = 0.f;
        for (int d = 0; d < 64; ++d)
            dot = fmaf(aws[k * 65 + d], arow[d], dot);
        out[b * 64 + k] = fmaxf(fmaf(inv, dot, agg_b[k]), 0.f);
    }
}

extern "C" void kernel_launch(void* const* d_in, const int* in_sizes, int n_in,
                              void* d_out, int out_size, void* d_ws, size_t ws_size,
                              hipStream_t stream) {
    const int*   iids     = (const int*)d_in[0];
    const int*   pad      = (const int*)d_in[1];
    const float* user_emb = (const float*)d_in[2];
    const float* item_emb = (const float*)d_in[3];
    const float* rate_emb = (const float*)d_in[4];
    const float* gu_w1    = (const float*)d_in[5];
    const float* gu_b1    = (const float*)d_in[6];
    const float* gu_w2    = (const float*)d_in[7];
    const float* gu_b2    = (const float*)d_in[8];
    const float* att_w1   = (const float*)d_in[9];
    const float* att_b1   = (const float*)d_in[10];
    const float* att_w2   = (const float*)d_in[11];
    const float* att_b2   = (const float*)d_in[12];
    const float* agg_w    = (const float*)d_in[13];
    const float* agg_b    = (const float*)d_in[14];
    float* ws  = (float*)d_ws;
    float* out = (float*)d_out;

    hipLaunchKernelGGL(prep_all, dim3(64), dim3(256), 0, stream,
                       gu_w1, gu_b1, gu_w2, att_w1, att_b1, gu_b2, rate_emb, ws);

    if (ws_size >= WS_NEED_BYTES) {
        hipLaunchKernelGGL((prep_h1u_qc<1>), dim3(NU_SZ / 16 + B_SZ), dim3(64), 0, stream,
                           user_emb, iids, item_emb, ws, ws + OFF_H1U, ws + OFF_QC);
        hipLaunchKernelGGL(fused_main3, dim3(B_SZ * 13), dim3(64), 0, stream,
                           pad, ws + OFF_H1U, gu_b2, att_w2, att_b2,
                           ws, ws + OFF_AGG, ws + OFF_SC);
    } else {
        hipLaunchKernelGGL((prep_h1u_qc<0>), dim3(B_SZ), dim3(64), 0, stream,
                           user_emb, iids, item_emb, ws, ws + OFF_QC, ws + OFF_QC);
        hipLaunchKernelGGL(fused_main1, dim3(B_SZ * 13), dim3(64), 0, stream,
                           pad, user_emb, gu_b2, att_b1, att_w2, att_b2,
                           ws, ws + OFF_AGG, ws + OFF_SC);
    }
    hipLaunchKernelGGL(final_z, dim3(B_SZ / 8), dim3(256), 0, stream,
                       ws + OFF_AGG, ws + OFF_SC, agg_w, agg_b, out);
}